// Round 3
// baseline (764.318 us; speedup 1.0000x reference)
//
#include <hip/hip_runtime.h>
#include <hip/hip_bf16.h>

#define SEQ  2048
#define DH   64
#define NBH  64          // B*H
#define NH   16
#define QT   16          // q-rows per block
#define NW   8           // waves per block
#define NT   (NW * 64)
#define PROW 1028        // padded dword stride of P rows in LDS

typedef __attribute__((ext_vector_type(8))) short short8;
typedef __attribute__((ext_vector_type(4))) float f32x4;

__device__ __forceinline__ unsigned short f2bf(float x) {
    union { float f; unsigned u; } c; c.f = x;
    return (unsigned short)((c.u + 0x7fffu + ((c.u >> 16) & 1u)) >> 16);
}
__device__ __forceinline__ unsigned pk2(float a, float b) {
    return (unsigned)f2bf(a) | ((unsigned)f2bf(b) << 16);
}

// ---- prepass: Q,K fp32 -> bf16 (same layout) ----
__global__ void prep_qk(const float* __restrict__ Q, const float* __restrict__ K,
                        unsigned short* __restrict__ Qb, unsigned short* __restrict__ Kb) {
    unsigned i4 = blockIdx.x * 256u + threadIdx.x;
    const float* src; unsigned short* dst;
    if (i4 < 2097152u) { src = Q; dst = Qb; }
    else { i4 -= 2097152u; src = K; dst = Kb; }
    float4 v = ((const float4*)src)[i4];
    ushort4 o; o.x = f2bf(v.x); o.y = f2bf(v.y); o.z = f2bf(v.z); o.w = f2bf(v.w);
    ((ushort4*)dst)[i4] = o;
}

// ---- prepass: V fp32 [bh][s][d] -> bf16 transposed [bh][d][s] ----
__global__ void prep_v(const float* __restrict__ V, unsigned short* __restrict__ VT) {
    __shared__ unsigned short tile[64][72];
    const int t = threadIdx.x;
    const int bh = blockIdx.x >> 5;
    const int s0 = (blockIdx.x & 31) * 64;
    const float* vb = V + ((size_t)bh * SEQ + s0) * DH;
    #pragma unroll
    for (int pp = 0; pp < 4; ++pp) {
        const int sr = pp * 16 + (t >> 4);
        const int dc = (t & 15) * 4;
        float4 v = *(const float4*)(vb + sr * DH + dc);
        tile[sr][dc]     = f2bf(v.x); tile[sr][dc + 1] = f2bf(v.y);
        tile[sr][dc + 2] = f2bf(v.z); tile[sr][dc + 3] = f2bf(v.w);
    }
    __syncthreads();
    const int d = t >> 2, c = (t & 3) * 16;
    short8 w0, w1;
    #pragma unroll
    for (int j = 0; j < 8; ++j) { w0[j] = (short)tile[c + j][d]; w1[j] = (short)tile[c + 8 + j][d]; }
    unsigned short* o = VT + ((size_t)bh * DH + d) * SEQ + s0 + c;
    *(short8*)o = w0; *(short8*)(o + 8) = w1;
}

// ---- prepass: mask int32 -> byte ----
__global__ void prep_m(const int* __restrict__ M, unsigned char* __restrict__ M8) {
    const unsigned i4 = blockIdx.x * 256u + threadIdx.x;
    int4 m = ((const int4*)M)[i4];
    uchar4 o; o.x = (unsigned char)(m.x != 0); o.y = (unsigned char)(m.y != 0);
    o.z = (unsigned char)(m.z != 0); o.w = (unsigned char)(m.w != 0);
    ((uchar4*)M8)[i4] = o;
}

template<bool PRE>
__global__ __launch_bounds__(NT, 4) void attn_main(
    const float* __restrict__ Qf, const float* __restrict__ Kf,
    const float* __restrict__ Vf, const int* __restrict__ Mi,
    const unsigned short* __restrict__ Qb, const unsigned short* __restrict__ Kb,
    const unsigned short* __restrict__ VT, const unsigned char* __restrict__ M8,
    float* __restrict__ O, float* __restrict__ W)
{
    // P matrix for the whole block: [16 q][2048 k] bf16, padded row stride 1028 dw
    __shared__ unsigned pl[QT * PROW];               // 65.8 KB
    __shared__ float redm[NW * 16], reds[NW * 16], rowRL[16];

    const int tid = threadIdx.x, wv = tid >> 6, ln = tid & 63;
    const int lr = ln & 15, lg = ln >> 4;
    // XCD-aware swizzle: 8192 blocks = 8 XCDs x 1024; contiguous work per XCD
    const int bid = ((blockIdx.x & 7) << 10) | (blockIdx.x >> 3);
    const int h = bid & 15, t2 = bid >> 4;
    const int qt = t2 & 127, b = t2 >> 7;
    const int bh = b * NH + h, q0 = qt * QT, k0 = wv * (SEQ / NW);

    // ---- Q as MFMA B-fragment (swapped QK^T): lane holds Q[q0+lr][8lg+i] ----
    short8 qf0, qf1;
    if (PRE) {
        const unsigned short* qp = Qb + ((size_t)bh * SEQ + q0 + lr) * DH + 8 * lg;
        qf0 = *(const short8*)qp; qf1 = *(const short8*)(qp + 32);
    } else {
        const float* qp = Qf + ((size_t)bh * SEQ + q0 + lr) * DH + 8 * lg;
        #pragma unroll
        for (int i = 0; i < 8; ++i) { qf0[i] = (short)f2bf(qp[i]); qf1[i] = (short)f2bf(qp[32 + i]); }
    }

    // ---- hoisted mask loads (overlap L2 latency with QK pipeline) ----
    uchar4 mq[16];
    if (PRE) {
        const unsigned char* mb = M8 + (size_t)b * SEQ * SEQ + (size_t)(q0 + lr) * SEQ + k0 + 4 * lg;
        #pragma unroll
        for (int kt = 0; kt < 16; ++kt) mq[kt] = *(const uchar4*)(mb + kt * 16);
    } else {
        const int* mb = Mi + (size_t)b * SEQ * SEQ + (size_t)(q0 + lr) * SEQ + k0 + 4 * lg;
        #pragma unroll
        for (int kt = 0; kt < 16; ++kt) {
            int4 mv = *(const int4*)(mb + kt * 16);
            mq[kt].x = (unsigned char)(mv.x != 0); mq[kt].y = (unsigned char)(mv.y != 0);
            mq[kt].z = (unsigned char)(mv.z != 0); mq[kt].w = (unsigned char)(mv.w != 0);
        }
    }

    // ---- scores in registers: p[kt][r] = P[q=lr][k = k0 + 16kt + 4lg + r] ----
    f32x4 p[16];
    #pragma unroll
    for (int kt = 0; kt < 16; ++kt) {
        short8 ka0, ka1;
        if (PRE) {
            const unsigned short* kp = Kb + ((size_t)bh * SEQ + k0 + kt * 16 + lr) * DH + 8 * lg;
            ka0 = *(const short8*)kp; ka1 = *(const short8*)(kp + 32);
        } else {
            const float* kp = Kf + ((size_t)bh * SEQ + k0 + kt * 16 + lr) * DH + 8 * lg;
            #pragma unroll
            for (int i = 0; i < 8; ++i) { ka0[i] = (short)f2bf(kp[i]); ka1[i] = (short)f2bf(kp[32 + i]); }
        }
        f32x4 a = {0.f, 0.f, 0.f, 0.f};
        a = __builtin_amdgcn_mfma_f32_16x16x32_bf16(ka0, qf0, a, 0, 0, 0);
        a = __builtin_amdgcn_mfma_f32_16x16x32_bf16(ka1, qf1, a, 0, 0, 0);
        p[kt][0] = mq[kt].x ? a[0] * 0.125f : -INFINITY;
        p[kt][1] = mq[kt].y ? a[1] * 0.125f : -INFINITY;
        p[kt][2] = mq[kt].z ? a[2] * 0.125f : -INFINITY;
        p[kt][3] = mq[kt].w ? a[3] * 0.125f : -INFINITY;
    }

    // ---- row max: in-lane + shfl + cross-wave LDS ----
    float m = -INFINITY;
    #pragma unroll
    for (int kt = 0; kt < 16; ++kt)
        m = fmaxf(m, fmaxf(fmaxf(p[kt][0], p[kt][1]), fmaxf(p[kt][2], p[kt][3])));
    m = fmaxf(m, __shfl_xor(m, 16));
    m = fmaxf(m, __shfl_xor(m, 32));
    if (ln < 16) redm[wv * 16 + ln] = m;
    __syncthreads();
    float mf = redm[lr];
    #pragma unroll
    for (int w = 1; w < NW; ++w) mf = fmaxf(mf, redm[w * 16 + lr]);

    // ---- exp + row sum ----
    float ls = 0.f;
    #pragma unroll
    for (int kt = 0; kt < 16; ++kt) {
        #pragma unroll
        for (int r = 0; r < 4; ++r) { float e = __expf(p[kt][r] - mf); p[kt][r] = e; ls += e; }
    }
    ls += __shfl_xor(ls, 16);
    ls += __shfl_xor(ls, 32);
    if (ln < 16) reds[wv * 16 + ln] = ls;
    __syncthreads();
    float l = reds[lr];
    #pragma unroll
    for (int w = 1; w < NW; ++w) l += reds[w * 16 + lr];
    const float rl = 1.f / l;
    if (wv == 0 && ln < 16) rowRL[ln] = rl;

    // ---- pack P (unnormalized exp, bf16) into full-block LDS matrix ----
    unsigned* pb = pl + lr * PROW + wv * 128 + 2 * lg;
    #pragma unroll
    for (int kt = 0; kt < 16; ++kt) {
        uint2 pk; pk.x = pk2(p[kt][0], p[kt][1]); pk.y = pk2(p[kt][2], p[kt][3]);
        *(uint2*)(pb + kt * 8) = pk;                 // ds_write_b64, 2-way (free)
    }
    __syncthreads();

    // ---- W write: wave owns 2 full rows -> contiguous 1KB wave-stores ----
    {
        const int wrow = 2 * wv + (ln >> 5);
        const int m32 = ln & 31;
        const float wrl = rowRL[wrow];
        float* Wr = W + (size_t)bh * SEQ * SEQ + (size_t)(q0 + wrow) * SEQ;
        const unsigned* pr = pl + wrow * PROW;
        #pragma unroll
        for (int j = 0; j < 8; ++j) {
            uint4 u = *(const uint4*)(pr + j * 128 + m32 * 4);
            float4 w0, w1;
            w0.x = __uint_as_float(u.x << 16) * wrl;
            w0.y = __uint_as_float(u.x & 0xffff0000u) * wrl;
            w0.z = __uint_as_float(u.y << 16) * wrl;
            w0.w = __uint_as_float(u.y & 0xffff0000u) * wrl;
            w1.x = __uint_as_float(u.z << 16) * wrl;
            w1.y = __uint_as_float(u.z & 0xffff0000u) * wrl;
            w1.z = __uint_as_float(u.w << 16) * wrl;
            w1.w = __uint_as_float(u.w & 0xffff0000u) * wrl;
            *(float4*)(Wr + j * 256 + 8 * m32) = w0;
            *(float4*)(Wr + j * 256 + 8 * m32 + 4) = w1;
        }
    }

    // ---- PV over this wave's 256-k slice (unnormalized P; scale O at end) ----
    f32x4 oa[4] = {{0.f,0.f,0.f,0.f},{0.f,0.f,0.f,0.f},{0.f,0.f,0.f,0.f},{0.f,0.f,0.f,0.f}};
    const unsigned* ab = pl + lr * PROW + wv * 128 + 4 * lg;
    #pragma unroll
    for (int s = 0; s < 8; ++s) {
        short8 af = *(const short8*)(ab + 16 * s);   // ds_read_b128
        if (PRE) {
            const unsigned short* vp = VT + (size_t)bh * DH * SEQ + k0 + 32 * s + 8 * lg;
            #pragma unroll
            for (int nb = 0; nb < 4; ++nb) {
                short8 bf = *(const short8*)(vp + (size_t)(nb * 16 + lr) * SEQ);
                oa[nb] = __builtin_amdgcn_mfma_f32_16x16x32_bf16(af, bf, oa[nb], 0, 0, 0);
            }
        } else {
            const float* vp = Vf + ((size_t)bh * SEQ + k0 + 32 * s + 8 * lg) * DH + lr;
            #pragma unroll
            for (int nb = 0; nb < 4; ++nb) {
                short8 bf;
                #pragma unroll
                for (int i = 0; i < 8; ++i) bf[i] = (short)f2bf(vp[i * DH + nb * 16]);
                oa[nb] = __builtin_amdgcn_mfma_f32_16x16x32_bf16(af, bf, oa[nb], 0, 0, 0);
            }
        }
    }

    // ---- cross-wave O reduction (reuse pl region; padded stride 65) ----
    __syncthreads();
    float* part = (float*)pl;
    #pragma unroll
    for (int nb = 0; nb < 4; ++nb)
        #pragma unroll
        for (int r = 0; r < 4; ++r)
            part[wv * 1040 + (4 * lg + r) * 65 + nb * 16 + lr] = oa[nb][r];
    __syncthreads();
    float* Ob = O + ((size_t)bh * SEQ + q0) * DH;
    for (int e = tid; e < QT * DH; e += NT) {
        const int q = e >> 6, d = e & 63;
        float sacc = 0.f;
        #pragma unroll
        for (int w = 0; w < NW; ++w) sacc += part[w * 1040 + q * 65 + d];
        Ob[e] = sacc * rowRL[q];
    }
}

extern "C" void kernel_launch(void* const* d_in, const int* in_sizes, int n_in,
                              void* d_out, int out_size, void* d_ws, size_t ws_size,
                              hipStream_t stream) {
    const float* Q = (const float*)d_in[0];
    const float* K = (const float*)d_in[1];
    const float* V = (const float*)d_in[2];
    const int*   M = (const int*)d_in[3];
    float* O = (float*)d_out;
    float* W = O + (size_t)NBH * SEQ * DH;

    const bool pre = ws_size >= (size_t)67108864;   // 64 MiB scratch layout
    unsigned short* Qb = (unsigned short*)d_ws;
    unsigned short* Kb = Qb + (size_t)8388608;
    unsigned short* VT = Qb + (size_t)2 * 8388608;
    unsigned char*  M8 = (unsigned char*)(Qb + (size_t)3 * 8388608);

    if (pre) {
        prep_qk<<<16384, 256, 0, stream>>>(Q, K, Qb, Kb);
        prep_v<<<2048, 256, 0, stream>>>(V, VT);
        prep_m<<<16384, 256, 0, stream>>>(M, M8);
        attn_main<true><<<8192, NT, 0, stream>>>(Q, K, V, M, Qb, Kb, VT, M8, O, W);
    } else {
        attn_main<false><<<8192, NT, 0, stream>>>(Q, K, V, M, nullptr, nullptr, nullptr, nullptr, O, W);
    }
}